// Round 4
// baseline (306.232 us; speedup 1.0000x reference)
//
#include <hip/hip_runtime.h>
#include <math.h>

typedef __attribute__((ext_vector_type(8))) short short8;
typedef __attribute__((ext_vector_type(4))) float f32x4;

#define B_   4
#define N_   1024
#define FTOT 3264
#define FPAD 3328

// workspace offsets (bytes)
#define WS_SS   0
#define WS_CG   256
#define WS_SX   4096
#define WS_ABF  151552
#define WS_PT   8540160
// total ws use: 35,803,136 bytes

__device__ __forceinline__ unsigned short f2bf(float x) {
  union { float f; unsigned u; } v; v.f = x;
  unsigned r = v.u + 0x7FFFu + ((v.u >> 16) & 1u);
  return (unsigned short)(r >> 16);
}

__device__ __forceinline__ void gload16(const void* gp, void* lp) {
  __builtin_amdgcn_global_load_lds((const __attribute__((address_space(1))) unsigned int*)gp,
                                   (__attribute__((address_space(3))) unsigned int*)lp, 16, 0, 0);
}

__device__ __forceinline__ float wave_sum(float v) {
#pragma unroll
  for (int off = 32; off > 0; off >>= 1) v += __shfl_down(v, off, 64);
  return v;
}

// ---------------- CG coefficient machinery ----------------
__device__ double dfact(int n) { double r = 1.0; for (int i = 2; i <= n; ++i) r *= (double)i; return r; }

__device__ float cg_coeff(int l1, int m1, int l2, int m2, int L, int M) {
  if (m1 + m2 != M) return 0.f;
  int dl = l1 - l2; if (dl < 0) dl = -dl;
  if (L < dl || L > l1 + l2) return 0.f;
  double pre = sqrt((double)(2*L+1) * dfact(L+l1-l2) * dfact(L-l1+l2) * dfact(l1+l2-L) / dfact(l1+l2+L+1));
  pre *= sqrt(dfact(L+M)*dfact(L-M)*dfact(l1-m1)*dfact(l1+m1)*dfact(l2-m2)*dfact(l2+m2));
  double s = 0.0;
  for (int k = 0; k <= l1 + l2 - L; ++k) {
    int d1 = l1+l2-L-k, d2 = l1-m1-k, d3 = l2+m2-k, d4 = L-l2+m1+k, d5 = L-l1-m2+k;
    if (d1 < 0 || d2 < 0 || d3 < 0 || d4 < 0 || d5 < 0) continue;
    double t = (k & 1) ? -1.0 : 1.0;
    t /= dfact(k)*dfact(d1)*dfact(d2)*dfact(d3)*dfact(d4)*dfact(d5);
    s += t;
  }
  return (float)(pre * s);
}

// 15 CG tables in (L, frag) order; dense [i][j][k] layout, offsets below.
__device__ const int t_l1[15]  = {0,1,2, 0,1,1,1,2,2, 0,1,1,2,2,2};
__device__ const int t_l2[15]  = {0,1,2, 1,0,1,2,1,2, 2,1,2,0,1,2};
__device__ const int t_L [15]  = {0,0,0, 1,1,1,1,1,1, 2,2,2,2,2,2};
__device__ const int t_off[16] = {0,1,10, 35,44,53,80,125,170, 245,270,315,390,415,490, 615};

// per-L frag decode tables (frag order = reference's (l1,l2) loop order)
__device__ const int d_l1[3][6]  = {{0,1,2,0,0,0},{0,1,1,1,2,2},{0,1,1,2,2,2}};
__device__ const int d_l2[3][6]  = {{0,1,2,0,0,0},{1,0,1,2,1,2},{2,1,2,0,1,2}};
__device__ const int d_off[3][6] = {{0,1,10,0,0,0},{35,44,53,80,125,170},{245,270,315,390,415,490}};
__device__ const int d_rb[3] = {0, 1, 4};   // row base of degree l in the 9-row (m) stack

// K0: zero sumsq accumulators + build CG table (runs every launch; graph-safe)
__global__ void k_init(float* ss, float* cg) {
  int tid = threadIdx.x;
  if (tid < 4) ss[tid] = 0.f;
  if (tid >= 615) return;
  int t = 0;
  while (t < 14 && tid >= t_off[t+1]) ++t;
  int local = tid - t_off[t];
  int l1 = t_l1[t], l2 = t_l2[t], L = t_L[t];
  int nk = 2*L+1, n2 = 2*l2+1;
  int k = local % nk; int rest = local / nk;
  int j = rest % n2;  int i = rest / n2;
  cg[tid] = cg_coeff(l1, i - l1, l2, j - l2, L, k - L);
}

// K1: sx[b,n,r] = sum_j s_l[b,n,j,m]  (r = stacked 9 m-rows)
// Persistent LDS-DMA pipeline: 256 blocks (1/CU), each handles 16 bn rows.
// Per step, the whole 36,864B (s0|s1|s2) row streams into LDS via 9
// global_load_lds sweeps/wave; vmcnt(9) keeps the next row's DMA in flight
// (never drains until tail) while the phase-reduce runs out of LDS.
#define SXWAIT_VM9 0x0F79   // vmcnt=9, expcnt/lgkmcnt nowait
#define SXWAIT_VM0 0x0F70   // vmcnt=0

__global__ __launch_bounds__(256) void k_sx(const float* __restrict__ s0p, const float* __restrict__ s1p,
                                            const float* __restrict__ s2p, float* __restrict__ sx) {
  __shared__ float stage[2][9216];   // [buf][A:1024 | B:3072 | C:5120]
  __shared__ float red[9][256];
  const int g   = blockIdx.x;        // 0..255
  const int bn0 = g * 16;
  const int tid = threadIdx.x;
  const int lane = tid & 63, w = tid >> 6;

#define SX_ISSUE(S, BUF) do { \
    const char* g0 = (const char*)(s0p + (size_t)(bn0 + (S)) * 1024) + w * 1024 + lane * 16; \
    const char* g1 = (const char*)(s1p + (size_t)(bn0 + (S)) * 3072) + w * 1024 + lane * 16; \
    const char* g2 = (const char*)(s2p + (size_t)(bn0 + (S)) * 5120) + w * 1024 + lane * 16; \
    char* lb = (char*)&stage[BUF][0] + w * 1024; \
    gload16(g0,         lb); \
    gload16(g1,         lb + 4096); \
    gload16(g1 + 4096,  lb + 8192); \
    gload16(g1 + 8192,  lb + 12288); \
    gload16(g2,         lb + 16384); \
    gload16(g2 + 4096,  lb + 20480); \
    gload16(g2 + 8192,  lb + 24576); \
    gload16(g2 + 12288, lb + 28672); \
    gload16(g2 + 16384, lb + 32768); \
  } while (0)

  SX_ISSUE(0, 0);
  SX_ISSUE(1, 1);
  for (int s = 0; s < 16; ++s) {
    const int buf = s & 1;
    if (s < 15) __builtin_amdgcn_s_waitcnt(SXWAIT_VM9);  // row s landed; row s+1 in flight
    else        __builtin_amdgcn_s_waitcnt(SXWAIT_VM0);
    __builtin_amdgcn_s_barrier();

    const float* base = &stage[buf][0];
    // A: all phase 0
    f32x4 va = *(const f32x4*)(base + tid * 4);
    // B: float idx 4tid+1024it+e, phase (tid+it+e)%3; slot u=(it+e)%3
    f32x4 vb[3];
#pragma unroll
    for (int it = 0; it < 3; ++it) vb[it] = *(const f32x4*)(base + 1024 + (tid + 256 * it) * 4);
    // C: float idx 4tid+1024it+e, phase (4tid+4it+e)%5; slot u=(4it+e)%5
    f32x4 vc[5];
#pragma unroll
    for (int it = 0; it < 5; ++it) vc[it] = *(const f32x4*)(base + 4096 + (tid + 256 * it) * 4);

    float a = va[0] + va[1] + va[2] + va[3];
    float b[3] = {0.f, 0.f, 0.f};
#pragma unroll
    for (int it = 0; it < 3; ++it)
#pragma unroll
      for (int e = 0; e < 4; ++e)
        b[(it + e) % 3] += vb[it][e];
    float c[5] = {0.f, 0.f, 0.f, 0.f, 0.f};
#pragma unroll
    for (int it = 0; it < 5; ++it)
#pragma unroll
      for (int e = 0; e < 4; ++e)
        c[(4 * it + e) % 5] += vc[it][e];

    // phase-indexed scatter (runtime rotation only in the LDS address)
    red[0][tid] = a;
    const int r3 = tid % 3;
#pragma unroll
    for (int u = 0; u < 3; ++u) red[1 + (r3 + u) % 3][tid] = b[u];
    const int q5 = (4 * tid) % 5;
#pragma unroll
    for (int u = 0; u < 5; ++u) red[4 + (q5 + u) % 5][tid] = c[u];
    __builtin_amdgcn_s_barrier();

    // wave w reduces rows w, w+4, w+8
    for (int r = w; r < 9; r += 4) {
      float v = red[r][lane] + red[r][lane + 64] + red[r][lane + 128] + red[r][lane + 192];
      v = wave_sum(v);
      if (lane == 0) sx[(size_t)(bn0 + s) * 9 + r] = v;
    }
    if (s < 14) SX_ISSUE(s + 2, buf);   // overwrite buf (reads consumed before barrier above)
  }
#undef SX_ISSUE
}

// K2: adjacency int32 -> bf16 in fragment-major tiled layout.
__global__ __launch_bounds__(256) void k_adj(const int* __restrict__ conn, unsigned short* __restrict__ Abf) {
  const int idx  = blockIdx.x * 256 + threadIdx.x;   // 0..524287
  const int lane = idx & 63;
  const int w    = (idx >> 6) & 2047;                // wave within batch
  const int b    = idx >> 17;
  const int nt16 = w >> 5;                           // 16-row n tile (0..63)
  const int ks   = w & 31;
  const int l16  = lane & 15, quad = lane >> 4;
  const int n    = nt16 * 16 + l16;
  const int m8   = ks * 32 + quad * 8;
  const int4* src = (const int4*)(conn + ((size_t)(b * 1024 + n) * 1024 + m8));
  int4 c0 = src[0], c1 = src[1];
  short8 o;
  o[0] = f2bf((float)c0.x); o[1] = f2bf((float)c0.y);
  o[2] = f2bf((float)c0.z); o[3] = f2bf((float)c0.w);
  o[4] = f2bf((float)c1.x); o[5] = f2bf((float)c1.y);
  o[6] = f2bf((float)c1.z); o[7] = f2bf((float)c1.w);
  const int nt = n >> 7, nr = n & 127;
  *(short8*)&Abf[(size_t)(b * 8 + nt) * 131072 + ks * 4096 +
                 ((nr >> 4) * 4 + quad) * 128 + (nr & 15) * 8] = o;
}

// K3: CG products -> PtT[b][ft(26)][ks(32)][fragment-major chunk] (bf16, padded to 3328)
#define VSTRIDE 148   // floats per m-row: 144 data + 4 pad

template <int L>
__device__ __forceinline__ void cg_emit(const float* __restrict__ vme, const float sxr[9],
                                        const float* __restrict__ cgt,
                                        unsigned short* __restrict__ pout, int cbase) {
  const int nfrag = (L == 0) ? 3 : 6;
  const int nk = 2 * L + 1;
  const int Lbase = (L == 0) ? 0 : (L == 1 ? 192 : 1344);
  const int Cfrag = nfrag * 64;
#pragma unroll
  for (int frag = 0; frag < nfrag; ++frag) {
    const int l1 = d_l1[L][frag], l2 = d_l2[L][frag];
    const int n1 = 2 * l1 + 1, n2 = 2 * l2 + 1;
    const int rb1 = d_rb[l1], rb2 = d_rb[l2];
    const int cgo = d_off[L][frag];
#pragma unroll
    for (int k = 0; k < nk; ++k) {
      float w[5];
#pragma unroll
      for (int i = 0; i < n1; ++i) {
        float a = 0.f;
#pragma unroll
        for (int j = 0; j < n2; ++j)
          a += sxr[rb2 + j] * cgt[cgo + (i * n2 + j) * nk + k];
        w[i] = a;
      }
      f32x4 val = {0.f, 0.f, 0.f, 0.f};
#pragma unroll
      for (int i = 0; i < n1; ++i) {
        f32x4 vv = *(const f32x4*)(vme + (rb1 + i) * 16);
        val += vv * w[i];
      }
      const int fb = Lbase + k * Cfrag + frag * 64 + cbase;
      const int ftile = fb >> 7, fr = fb & 127;
      unsigned short* pp = pout + (size_t)ftile * 131072 + (fr >> 4) * 512 + (fr & 15) * 8;
#pragma unroll
      for (int cc = 0; cc < 4; ++cc)
        pp[cc * 8] = f2bf(val[cc]);
    }
  }
}

__global__ __launch_bounds__(256) void k_cgp(const float* __restrict__ v0, const float* __restrict__ v1,
                                             const float* __restrict__ v2, const float* __restrict__ sx,
                                             const float* __restrict__ cgt, unsigned short* __restrict__ Pt) {
  __shared__ float vsh[64 * VSTRIDE];
  const int half = blockIdx.x & 1;
  const int cq   = blockIdx.x >> 1;
  const int mt   = blockIdx.y;
  const int b    = blockIdx.z;
  const int m0 = mt * 64;
  const int c0 = cq * 16;
  const int tid = threadIdx.x;
  const size_t nb = (size_t)b * N_ + m0;

  for (int e = tid; e < 9216; e += 256) {
    const int m = e / 144, rest = e % 144;
    const int r = rest >> 4, cc = rest & 15;
    float val;
    if (r == 0)      val = v0[(nb + m) * 64 + c0 + cc];
    else if (r < 4)  val = v1[((nb + m) * 3 + (r - 1)) * 64 + c0 + cc];
    else             val = v2[((nb + m) * 5 + (r - 4)) * 64 + c0 + cc];
    vsh[m * VSTRIDE + rest] = val;
  }
  const int lane = tid & 63, wv = tid >> 6;
  float sxr[9];
#pragma unroll
  for (int r = 0; r < 9; ++r) sxr[r] = sx[(nb + lane) * 9 + r];
  __syncthreads();

  const int ks = mt * 2 + (lane >> 5);
  const int kq = ((lane & 31) >> 3) * 128 + (lane & 7);
  unsigned short* pout = Pt + (size_t)b * 26 * 131072 + ks * 4096 + kq;
  const int cbase = c0 + wv * 4;
  const float* vme = &vsh[lane * VSTRIDE + wv * 4];

  if (half == 0) {
    cg_emit<0>(vme, sxr, cgt, pout, cbase);
    cg_emit<1>(vme, sxr, cgt, pout, cbase);
  } else {
    cg_emit<2>(vme, sxr, cgt, pout, cbase);
    const int fr = 64 + cbase;
    unsigned short* pp = pout + (size_t)25 * 131072 + (fr >> 4) * 512 + (fr & 15) * 8;
#pragma unroll
    for (int cc = 0; cc < 4; ++cc)
      pp[cc * 8] = 0;
  }
}

// K4: mp[b][n][f] = sum_m PtT*AbT.  256x256 tile, BK=64, 512 thr (8 waves 2x4),
// LDS 128KB (2-stage dbuf), vmcnt(8) depth-2 pipeline (never drains until tail),
// fragment-major LDS -> conflict-free ds_read_b128. One round: 208 blocks.
#define WAIT_VM8 0x0F78   // vmcnt=8, expcnt/lgkmcnt nowait
#define WAIT_VM0 0x0F70   // vmcnt=0

__global__ __launch_bounds__(512, 2) void k_gemm(const unsigned short* __restrict__ PtT,
                                                 const unsigned short* __restrict__ AbT,
                                                 float* __restrict__ out, float* __restrict__ ssv) {
  __shared__ unsigned short As[2][2][8192];   // [buf][h: f-half 128 rows][2 ks-chunks]
  __shared__ unsigned short Bs[2][2][8192];   // [buf][h: n-half 128 rows][2 ks-chunks]
  const int i  = blockIdx.x;          // 0..207
  const int x  = i & 7, j = i >> 3;   // x: XCD bucket, j: 0..25
  const int b   = x >> 1;
  const int ntp = 2 * (x & 1) + (j & 1);   // 0..3  (256-n tile)
  const int ftp = j >> 1;                  // 0..12 (256-f tile)
  const int f0 = ftp * 256, n0 = ntp * 256;
  const int tid  = threadIdx.x;
  const int w    = tid >> 6, lane = tid & 63;
  const int wr   = w >> 2, wc = w & 3;     // wave grid 2(M) x 4(N)
  const int l16  = lane & 15, quad = lane >> 4;

  const unsigned short* gA0 = PtT + (size_t)(b * 26 + 2 * ftp    ) * 131072;
  const unsigned short* gA1 = PtT + (size_t)(b * 26 + 2 * ftp + 1) * 131072;
  const unsigned short* gB0 = AbT + (size_t)(b * 8  + 2 * ntp    ) * 131072;
  const unsigned short* gB1 = AbT + (size_t)(b * 8  + 2 * ntp + 1) * 131072;
  const int so = w * 512 + lane * 8;   // per-thread global short offset within a round

#define ISSUE(T, BUF) do { \
    const size_t o = (size_t)(T) * 8192 + so; \
    gload16(gA0 + o,        &As[BUF][0][w * 512]); \
    gload16(gA0 + o + 4096, &As[BUF][0][4096 + w * 512]); \
    gload16(gA1 + o,        &As[BUF][1][w * 512]); \
    gload16(gA1 + o + 4096, &As[BUF][1][4096 + w * 512]); \
    gload16(gB0 + o,        &Bs[BUF][0][w * 512]); \
    gload16(gB0 + o + 4096, &Bs[BUF][0][4096 + w * 512]); \
    gload16(gB1 + o,        &Bs[BUF][1][w * 512]); \
    gload16(gB1 + o + 4096, &Bs[BUF][1][4096 + w * 512]); \
  } while (0)

  f32x4 acc[8][4] = {};
  const int bh  = wc >> 1;            // B half this wave reads
  const int bl4 = (wc & 1) * 4;       // 16-row group base within that half

#define COMPUTE(BUF) do { \
    _Pragma("unroll") \
    for (int kc = 0; kc < 2; ++kc) { \
      short8 bf[4]; \
      _Pragma("unroll") \
      for (int ni = 0; ni < 4; ++ni) \
        bf[ni] = *(const short8*)&Bs[BUF][bh][kc*4096 + ((bl4 + ni)*4 + quad)*128 + l16*8]; \
      _Pragma("unroll") \
      for (int mh = 0; mh < 2; ++mh) { \
        short8 af[4]; \
        _Pragma("unroll") \
        for (int m = 0; m < 4; ++m) \
          af[m] = *(const short8*)&As[BUF][wr][kc*4096 + ((mh*4 + m)*4 + quad)*128 + l16*8]; \
        _Pragma("unroll") \
        for (int m = 0; m < 4; ++m) \
          _Pragma("unroll") \
          for (int ni = 0; ni < 4; ++ni) \
            acc[mh*4 + m][ni] = __builtin_amdgcn_mfma_f32_16x16x32_bf16(af[m], bf[ni], acc[mh*4 + m][ni], 0, 0, 0); \
      } \
    } \
  } while (0)

  ISSUE(0, 0);
  ISSUE(1, 1);
  for (int t = 0; t < 15; ++t) {
    const int buf = t & 1;
    __builtin_amdgcn_s_waitcnt(WAIT_VM8);   // tile t landed; tile t+1 stays in flight
    __builtin_amdgcn_s_barrier();
    COMPUTE(buf);
    __builtin_amdgcn_s_barrier();           // all waves done reading buf
    if (t < 14) ISSUE(t + 2, buf);
  }
  __builtin_amdgcn_s_waitcnt(WAIT_VM0);     // tail: tile 15
  __builtin_amdgcn_s_barrier();
  COMPUTE(1);

  // epilogue: D[row=f_local][col=n_local], row = quad*4+reg, col = lane&15 (m89-verified)
  float ssl0 = 0.f, ssl1 = 0.f, ssl2 = 0.f;
#pragma unroll
  for (int mi = 0; mi < 8; ++mi) {
    const int fbase = f0 + wr*128 + mi*16 + quad*4;   // L boundaries are 16-aligned
    if (fbase >= FTOT) continue;
    float sq = 0.f;
#pragma unroll
    for (int ni = 0; ni < 4; ++ni) {
      const int n = n0 + wc*64 + ni*16 + l16;
      f32x4 v = acc[mi][ni];
      sq += v[0]*v[0] + v[1]*v[1] + v[2]*v[2] + v[3]*v[3];
      *(f32x4*)&out[((size_t)b * N_ + n) * FTOT + fbase] = v;
    }
    if (fbase < 192) ssl0 += sq; else if (fbase < 1344) ssl1 += sq; else ssl2 += sq;
  }
  ssl0 = wave_sum(ssl0); ssl1 = wave_sum(ssl1); ssl2 = wave_sum(ssl2);

  // block-level reduction of the 3 sums -> 3 atomics per block (624 total)
  __syncthreads();                           // LDS free for reuse
  float* red = (float*)&As[0][0][0];
  if (lane == 0) { red[w*3 + 0] = ssl0; red[w*3 + 1] = ssl1; red[w*3 + 2] = ssl2; }
  __syncthreads();
  if (tid < 3) {
    float s = 0.f;
#pragma unroll
    for (int ww = 0; ww < 8; ++ww) s += red[ww*3 + tid];
    if (s != 0.f) atomicAdd(&ssv[tid], s);
  }
#undef ISSUE
#undef COMPUTE
}

// K5: in-place scale by 64 / ((2L+1)*||mp_L||_F)
__global__ __launch_bounds__(256) void k_scale(float* __restrict__ out, const float* __restrict__ ssv) {
  const int idx = blockIdx.x * 256 + threadIdx.x;   // float4 index
  const int total = B_ * N_ * (FTOT / 4);
  if (idx >= total) return;
  const int f = (idx % (FTOT / 4)) * 4;
  const int L = f < 192 ? 0 : (f < 1344 ? 1 : 2);
  const float sc = 64.f / ((float)(2*L+1) * sqrtf(ssv[L]));
  f32x4* p = (f32x4*)out + idx;
  f32x4 v = *p;
  v *= sc;
  *p = v;
}

extern "C" void kernel_launch(void* const* d_in, const int* in_sizes, int n_in,
                              void* d_out, int out_size, void* d_ws, size_t ws_size,
                              hipStream_t stream) {
  const float* v0 = (const float*)d_in[0];
  const float* v1 = (const float*)d_in[1];
  const float* v2 = (const float*)d_in[2];
  const float* s0 = (const float*)d_in[3];
  const float* s1 = (const float*)d_in[4];
  const float* s2 = (const float*)d_in[5];
  const int* conn = (const int*)d_in[6];
  char* ws = (char*)d_ws;
  float* ss            = (float*)(ws + WS_SS);
  float* cg            = (float*)(ws + WS_CG);
  float* sx            = (float*)(ws + WS_SX);
  unsigned short* Abf  = (unsigned short*)(ws + WS_ABF);
  unsigned short* Pt   = (unsigned short*)(ws + WS_PT);
  float* out = (float*)d_out;

  k_init <<<dim3(1),            dim3(640), 0, stream>>>(ss, cg);
  k_sx   <<<dim3(256),          dim3(256), 0, stream>>>(s0, s1, s2, sx);
  k_adj  <<<dim3(2048),         dim3(256), 0, stream>>>(conn, Abf);
  k_cgp  <<<dim3(8, 16, B_),    dim3(256), 0, stream>>>(v0, v1, v2, sx, cg, Pt);
  k_gemm <<<dim3(208),          dim3(512), 0, stream>>>(Pt, Abf, out, ss);
  k_scale<<<dim3(13056),        dim3(256), 0, stream>>>(out, ss);
}

// Round 5
// 277.754 us; speedup vs baseline: 1.1025x; 1.1025x over previous
//
#include <hip/hip_runtime.h>
#include <math.h>

typedef __attribute__((ext_vector_type(8))) short short8;
typedef __attribute__((ext_vector_type(4))) float f32x4;

#define B_   4
#define N_   1024
#define FTOT 3264
#define FPAD 3328

// workspace offsets (bytes)
#define WS_SS   0
#define WS_CG   256
#define WS_SX   4096
#define WS_ABF  151552
#define WS_PT   8540160
// total ws use: 35,803,136 bytes

__device__ __forceinline__ unsigned short f2bf(float x) {
  union { float f; unsigned u; } v; v.f = x;
  unsigned r = v.u + 0x7FFFu + ((v.u >> 16) & 1u);
  return (unsigned short)(r >> 16);
}

__device__ __forceinline__ void gload16(const void* gp, void* lp) {
  __builtin_amdgcn_global_load_lds((const __attribute__((address_space(1))) unsigned int*)gp,
                                   (__attribute__((address_space(3))) unsigned int*)lp, 16, 0, 0);
}

__device__ __forceinline__ float wave_sum(float v) {
#pragma unroll
  for (int off = 32; off > 0; off >>= 1) v += __shfl_down(v, off, 64);
  return v;
}

// ---------------- CG coefficient machinery ----------------
__device__ double dfact(int n) { double r = 1.0; for (int i = 2; i <= n; ++i) r *= (double)i; return r; }

__device__ float cg_coeff(int l1, int m1, int l2, int m2, int L, int M) {
  if (m1 + m2 != M) return 0.f;
  int dl = l1 - l2; if (dl < 0) dl = -dl;
  if (L < dl || L > l1 + l2) return 0.f;
  double pre = sqrt((double)(2*L+1) * dfact(L+l1-l2) * dfact(L-l1+l2) * dfact(l1+l2-L) / dfact(l1+l2+L+1));
  pre *= sqrt(dfact(L+M)*dfact(L-M)*dfact(l1-m1)*dfact(l1+m1)*dfact(l2-m2)*dfact(l2+m2));
  double s = 0.0;
  for (int k = 0; k <= l1 + l2 - L; ++k) {
    int d1 = l1+l2-L-k, d2 = l1-m1-k, d3 = l2+m2-k, d4 = L-l2+m1+k, d5 = L-l1-m2+k;
    if (d1 < 0 || d2 < 0 || d3 < 0 || d4 < 0 || d5 < 0) continue;
    double t = (k & 1) ? -1.0 : 1.0;
    t /= dfact(k)*dfact(d1)*dfact(d2)*dfact(d3)*dfact(d4)*dfact(d5);
    s += t;
  }
  return (float)(pre * s);
}

// 15 CG tables in (L, frag) order; dense [i][j][k] layout, offsets below.
__device__ const int t_l1[15]  = {0,1,2, 0,1,1,1,2,2, 0,1,1,2,2,2};
__device__ const int t_l2[15]  = {0,1,2, 1,0,1,2,1,2, 2,1,2,0,1,2};
__device__ const int t_L [15]  = {0,0,0, 1,1,1,1,1,1, 2,2,2,2,2,2};
__device__ const int t_off[16] = {0,1,10, 35,44,53,80,125,170, 245,270,315,390,415,490, 615};

// per-L frag decode tables (frag order = reference's (l1,l2) loop order)
__device__ const int d_l1[3][6]  = {{0,1,2,0,0,0},{0,1,1,1,2,2},{0,1,1,2,2,2}};
__device__ const int d_l2[3][6]  = {{0,1,2,0,0,0},{1,0,1,2,1,2},{2,1,2,0,1,2}};
__device__ const int d_off[3][6] = {{0,1,10,0,0,0},{35,44,53,80,125,170},{245,270,315,390,415,490}};
__device__ const int d_rb[3] = {0, 1, 4};   // row base of degree l in the 9-row (m) stack

// K_pre: fused k_sx (blocks 0..4095) + k_adj (blocks 4096..6143) + init (block 4096).
// sx part: float4 loads (9/thread, independent), compile-time phase slots,
// single barrier, wave-level final reduce (round-3 proven form, 56us).
__global__ __launch_bounds__(256) void k_pre(const float* __restrict__ s0p, const float* __restrict__ s1p,
                                             const float* __restrict__ s2p, float* __restrict__ sx,
                                             const int* __restrict__ conn, unsigned short* __restrict__ Abf,
                                             float* __restrict__ ss, float* __restrict__ cg) {
  __shared__ float red[9][256];
  const int tid = threadIdx.x;

  if (blockIdx.x < 4096) {
    const int bn = blockIdx.x;
    const f32x4* p0 = (const f32x4*)(s0p + (size_t)bn * 1024);
    const f32x4* p1 = (const f32x4*)(s1p + (size_t)bn * 3072);
    const f32x4* p2 = (const f32x4*)(s2p + (size_t)bn * 5120);

    // issue all 9 loads up front (independent -> deep vmcnt pipeline)
    f32x4 va = p0[tid];
    f32x4 vb[3];
#pragma unroll
    for (int it = 0; it < 3; ++it) vb[it] = p1[tid + 256 * it];
    f32x4 vc[5];
#pragma unroll
    for (int it = 0; it < 5; ++it) vc[it] = p2[tid + 256 * it];

    // s0: all elements are phase 0
    float a = va[0] + va[1] + va[2] + va[3];

    // s1: float idx = 4*tid + 1024*it + e; phase = (tid + it + e) mod 3; slot u=(it+e)%3
    float b[3] = {0.f, 0.f, 0.f};
#pragma unroll
    for (int it = 0; it < 3; ++it)
#pragma unroll
      for (int e = 0; e < 4; ++e)
        b[(it + e) % 3] += vb[it][e];

    // s2: float idx = 4*tid + 1024*it + e; phase = (4*tid + 4*it + e) mod 5; slot u=(4it+e)%5
    float c[5] = {0.f, 0.f, 0.f, 0.f, 0.f};
#pragma unroll
    for (int it = 0; it < 5; ++it)
#pragma unroll
      for (int e = 0; e < 4; ++e)
        c[(4 * it + e) % 5] += vc[it][e];

    // phase-indexed scatter (runtime rotation only in the LDS address)
    red[0][tid] = a;
    const int r3 = tid % 3;
#pragma unroll
    for (int u = 0; u < 3; ++u) red[1 + (r3 + u) % 3][tid] = b[u];
    const int q5 = (4 * tid) % 5;
#pragma unroll
    for (int u = 0; u < 5; ++u) red[4 + (q5 + u) % 5][tid] = c[u];
    __syncthreads();

    // wave w reduces rows w, w+4, w+8 (no further barriers)
    const int lane = tid & 63, w = tid >> 6;
    for (int r = w; r < 9; r += 4) {
      float v = red[r][lane] + red[r][lane + 64] + red[r][lane + 128] + red[r][lane + 192];
      v = wave_sum(v);
      if (lane == 0) sx[(size_t)bn * 9 + r] = v;
    }
    return;
  }

  // ---- adjacency part (blocks 4096..6143) ----
  const int idx  = (blockIdx.x - 4096) * 256 + tid;   // 0..524287
  const int lane = idx & 63;
  const int w    = (idx >> 6) & 2047;                 // wave within batch
  const int b    = idx >> 17;
  const int nt16 = w >> 5;                            // 16-row n tile (0..63)
  const int ks   = w & 31;
  const int l16  = lane & 15, quad = lane >> 4;
  const int n    = nt16 * 16 + l16;
  const int m8   = ks * 32 + quad * 8;
  const int4* src = (const int4*)(conn + ((size_t)(b * 1024 + n) * 1024 + m8));
  int4 c0 = src[0], c1 = src[1];
  short8 o;
  o[0] = f2bf((float)c0.x); o[1] = f2bf((float)c0.y);
  o[2] = f2bf((float)c0.z); o[3] = f2bf((float)c0.w);
  o[4] = f2bf((float)c1.x); o[5] = f2bf((float)c1.y);
  o[6] = f2bf((float)c1.z); o[7] = f2bf((float)c1.w);
  const int nt = n >> 7, nr = n & 127;
  *(short8*)&Abf[(size_t)(b * 8 + nt) * 131072 + ks * 4096 +
                 ((nr >> 4) * 4 + quad) * 128 + (nr & 15) * 8] = o;

  // ---- init part (block 4096 only): zero ss + build CG table ----
  if (blockIdx.x == 4096) {
    if (tid < 4) ss[tid] = 0.f;
    for (int t0 = tid; t0 < 615; t0 += 256) {
      int t = 0;
      while (t < 14 && t0 >= t_off[t+1]) ++t;
      int local = t0 - t_off[t];
      int l1 = t_l1[t], l2 = t_l2[t], L = t_L[t];
      int nk = 2*L+1, n2 = 2*l2+1;
      int k = local % nk; int rest = local / nk;
      int j = rest % n2;  int i = rest / n2;
      cg[t0] = cg_coeff(l1, i - l1, l2, j - l2, L, k - L);
    }
  }
}

// K3: CG products -> PtT[b][ft(26)][ks(32)][fragment-major chunk] (bf16, padded to 3328)
#define VSTRIDE 148   // floats per m-row: 144 data + 4 pad

template <int L>
__device__ __forceinline__ void cg_emit(const float* __restrict__ vme, const float sxr[9],
                                        const float* __restrict__ cgt,
                                        unsigned short* __restrict__ pout, int cbase) {
  const int nfrag = (L == 0) ? 3 : 6;
  const int nk = 2 * L + 1;
  const int Lbase = (L == 0) ? 0 : (L == 1 ? 192 : 1344);
  const int Cfrag = nfrag * 64;
#pragma unroll
  for (int frag = 0; frag < nfrag; ++frag) {
    const int l1 = d_l1[L][frag], l2 = d_l2[L][frag];
    const int n1 = 2 * l1 + 1, n2 = 2 * l2 + 1;
    const int rb1 = d_rb[l1], rb2 = d_rb[l2];
    const int cgo = d_off[L][frag];
#pragma unroll
    for (int k = 0; k < nk; ++k) {
      float w[5];
#pragma unroll
      for (int i = 0; i < n1; ++i) {
        float a = 0.f;
#pragma unroll
        for (int j = 0; j < n2; ++j)
          a += sxr[rb2 + j] * cgt[cgo + (i * n2 + j) * nk + k];
        w[i] = a;
      }
      f32x4 val = {0.f, 0.f, 0.f, 0.f};
#pragma unroll
      for (int i = 0; i < n1; ++i) {
        f32x4 vv = *(const f32x4*)(vme + (rb1 + i) * 16);
        val += vv * w[i];
      }
      const int fb = Lbase + k * Cfrag + frag * 64 + cbase;
      const int ftile = fb >> 7, fr = fb & 127;
      unsigned short* pp = pout + (size_t)ftile * 131072 + (fr >> 4) * 512 + (fr & 15) * 8;
#pragma unroll
      for (int cc = 0; cc < 4; ++cc)
        pp[cc * 8] = f2bf(val[cc]);
    }
  }
}

__global__ __launch_bounds__(256) void k_cgp(const float* __restrict__ v0, const float* __restrict__ v1,
                                             const float* __restrict__ v2, const float* __restrict__ sx,
                                             const float* __restrict__ cgt, unsigned short* __restrict__ Pt) {
  __shared__ float vsh[64 * VSTRIDE];
  const int half = blockIdx.x & 1;
  const int cq   = blockIdx.x >> 1;
  const int mt   = blockIdx.y;
  const int b    = blockIdx.z;
  const int m0 = mt * 64;
  const int c0 = cq * 16;
  const int tid = threadIdx.x;
  const size_t nb = (size_t)b * N_ + m0;

  // vectorized v-tile load+transpose: thread = (m, c-quad); 9 aligned f32x4 each
  {
    const int mloc = tid >> 2;            // 0..63
    const int cc0  = (tid & 3) * 4;       // 0,4,8,12
    const size_t vrow = nb + mloc;
    *(f32x4*)&vsh[mloc*VSTRIDE + 0*16 + cc0] = *(const f32x4*)&v0[vrow * 64 + c0 + cc0];
#pragma unroll
    for (int r = 1; r < 4; ++r)
      *(f32x4*)&vsh[mloc*VSTRIDE + r*16 + cc0] = *(const f32x4*)&v1[(vrow * 3 + (r-1)) * 64 + c0 + cc0];
#pragma unroll
    for (int r = 4; r < 9; ++r)
      *(f32x4*)&vsh[mloc*VSTRIDE + r*16 + cc0] = *(const f32x4*)&v2[(vrow * 5 + (r-4)) * 64 + c0 + cc0];
  }
  const int lane = tid & 63, wv = tid >> 6;
  float sxr[9];
#pragma unroll
  for (int r = 0; r < 9; ++r) sxr[r] = sx[(nb + lane) * 9 + r];
  __syncthreads();

  const int ks = mt * 2 + (lane >> 5);
  const int kq = ((lane & 31) >> 3) * 128 + (lane & 7);
  unsigned short* pout = Pt + (size_t)b * 26 * 131072 + ks * 4096 + kq;
  const int cbase = c0 + wv * 4;
  const float* vme = &vsh[lane * VSTRIDE + wv * 4];

  if (half == 0) {
    cg_emit<0>(vme, sxr, cgt, pout, cbase);
    cg_emit<1>(vme, sxr, cgt, pout, cbase);
  } else {
    cg_emit<2>(vme, sxr, cgt, pout, cbase);
    const int fr = 64 + cbase;
    unsigned short* pp = pout + (size_t)25 * 131072 + (fr >> 4) * 512 + (fr & 15) * 8;
#pragma unroll
    for (int cc = 0; cc < 4; ++cc)
      pp[cc * 8] = 0;
  }
}

// K4: mp[b][n][f] = sum_m PtT*AbT.  256x256 tile, BK=64, 512 thr (8 waves 2x4),
// LDS 128KB (2-stage dbuf), vmcnt(8) depth-2 pipeline (never drains until tail),
// fragment-major LDS -> conflict-free ds_read_b128. One round: 208 blocks.
#define WAIT_VM8 0x0F78   // vmcnt=8, expcnt/lgkmcnt nowait
#define WAIT_VM0 0x0F70   // vmcnt=0

__global__ __launch_bounds__(512, 2) void k_gemm(const unsigned short* __restrict__ PtT,
                                                 const unsigned short* __restrict__ AbT,
                                                 float* __restrict__ out, float* __restrict__ ssv) {
  __shared__ unsigned short As[2][2][8192];   // [buf][h: f-half 128 rows][2 ks-chunks]
  __shared__ unsigned short Bs[2][2][8192];   // [buf][h: n-half 128 rows][2 ks-chunks]
  const int i  = blockIdx.x;          // 0..207
  const int x  = i & 7, j = i >> 3;   // x: XCD bucket, j: 0..25
  const int b   = x >> 1;
  const int ntp = 2 * (x & 1) + (j & 1);   // 0..3  (256-n tile)
  const int ftp = j >> 1;                  // 0..12 (256-f tile)
  const int f0 = ftp * 256, n0 = ntp * 256;
  const int tid  = threadIdx.x;
  const int w    = tid >> 6, lane = tid & 63;
  const int wr   = w >> 2, wc = w & 3;     // wave grid 2(M) x 4(N)
  const int l16  = lane & 15, quad = lane >> 4;

  const unsigned short* gA0 = PtT + (size_t)(b * 26 + 2 * ftp    ) * 131072;
  const unsigned short* gA1 = PtT + (size_t)(b * 26 + 2 * ftp + 1) * 131072;
  const unsigned short* gB0 = AbT + (size_t)(b * 8  + 2 * ntp    ) * 131072;
  const unsigned short* gB1 = AbT + (size_t)(b * 8  + 2 * ntp + 1) * 131072;
  const int so = w * 512 + lane * 8;   // per-thread global short offset within a round

#define ISSUE(T, BUF) do { \
    const size_t o = (size_t)(T) * 8192 + so; \
    gload16(gA0 + o,        &As[BUF][0][w * 512]); \
    gload16(gA0 + o + 4096, &As[BUF][0][4096 + w * 512]); \
    gload16(gA1 + o,        &As[BUF][1][w * 512]); \
    gload16(gA1 + o + 4096, &As[BUF][1][4096 + w * 512]); \
    gload16(gB0 + o,        &Bs[BUF][0][w * 512]); \
    gload16(gB0 + o + 4096, &Bs[BUF][0][4096 + w * 512]); \
    gload16(gB1 + o,        &Bs[BUF][1][w * 512]); \
    gload16(gB1 + o + 4096, &Bs[BUF][1][4096 + w * 512]); \
  } while (0)

  f32x4 acc[8][4] = {};
  const int bh  = wc >> 1;            // B half this wave reads
  const int bl4 = (wc & 1) * 4;       // 16-row group base within that half

#define COMPUTE(BUF) do { \
    _Pragma("unroll") \
    for (int kc = 0; kc < 2; ++kc) { \
      short8 bf[4]; \
      _Pragma("unroll") \
      for (int ni = 0; ni < 4; ++ni) \
        bf[ni] = *(const short8*)&Bs[BUF][bh][kc*4096 + ((bl4 + ni)*4 + quad)*128 + l16*8]; \
      _Pragma("unroll") \
      for (int mh = 0; mh < 2; ++mh) { \
        short8 af[4]; \
        _Pragma("unroll") \
        for (int m = 0; m < 4; ++m) \
          af[m] = *(const short8*)&As[BUF][wr][kc*4096 + ((mh*4 + m)*4 + quad)*128 + l16*8]; \
        _Pragma("unroll") \
        for (int m = 0; m < 4; ++m) \
          _Pragma("unroll") \
          for (int ni = 0; ni < 4; ++ni) \
            acc[mh*4 + m][ni] = __builtin_amdgcn_mfma_f32_16x16x32_bf16(af[m], bf[ni], acc[mh*4 + m][ni], 0, 0, 0); \
      } \
    } \
  } while (0)

  ISSUE(0, 0);
  ISSUE(1, 1);
  for (int t = 0; t < 15; ++t) {
    const int buf = t & 1;
    __builtin_amdgcn_s_waitcnt(WAIT_VM8);   // tile t landed; tile t+1 stays in flight
    __builtin_amdgcn_s_barrier();
    COMPUTE(buf);
    __builtin_amdgcn_s_barrier();           // all waves done reading buf
    if (t < 14) ISSUE(t + 2, buf);
  }
  __builtin_amdgcn_s_waitcnt(WAIT_VM0);     // tail: tile 15
  __builtin_amdgcn_s_barrier();
  COMPUTE(1);

  // epilogue: D[row=f_local][col=n_local], row = quad*4+reg, col = lane&15 (m89-verified)
  float ssl0 = 0.f, ssl1 = 0.f, ssl2 = 0.f;
#pragma unroll
  for (int mi = 0; mi < 8; ++mi) {
    const int fbase = f0 + wr*128 + mi*16 + quad*4;   // L boundaries are 16-aligned
    if (fbase >= FTOT) continue;
    float sq = 0.f;
#pragma unroll
    for (int ni = 0; ni < 4; ++ni) {
      const int n = n0 + wc*64 + ni*16 + l16;
      f32x4 v = acc[mi][ni];
      sq += v[0]*v[0] + v[1]*v[1] + v[2]*v[2] + v[3]*v[3];
      *(f32x4*)&out[((size_t)b * N_ + n) * FTOT + fbase] = v;
    }
    if (fbase < 192) ssl0 += sq; else if (fbase < 1344) ssl1 += sq; else ssl2 += sq;
  }
  ssl0 = wave_sum(ssl0); ssl1 = wave_sum(ssl1); ssl2 = wave_sum(ssl2);

  // block-level reduction of the 3 sums -> 3 atomics per block (624 total)
  __syncthreads();                           // LDS free for reuse
  float* red = (float*)&As[0][0][0];
  if (lane == 0) { red[w*3 + 0] = ssl0; red[w*3 + 1] = ssl1; red[w*3 + 2] = ssl2; }
  __syncthreads();
  if (tid < 3) {
    float s = 0.f;
#pragma unroll
    for (int ww = 0; ww < 8; ++ww) s += red[ww*3 + tid];
    if (s != 0.f) atomicAdd(&ssv[tid], s);
  }
#undef ISSUE
#undef COMPUTE
}

// K5: in-place scale by 64 / ((2L+1)*||mp_L||_F)
__global__ __launch_bounds__(256) void k_scale(float* __restrict__ out, const float* __restrict__ ssv) {
  const int idx = blockIdx.x * 256 + threadIdx.x;   // float4 index
  const int total = B_ * N_ * (FTOT / 4);
  if (idx >= total) return;
  const int f = (idx % (FTOT / 4)) * 4;
  const int L = f < 192 ? 0 : (f < 1344 ? 1 : 2);
  const float sc = 64.f / ((float)(2*L+1) * sqrtf(ssv[L]));
  f32x4* p = (f32x4*)out + idx;
  f32x4 v = *p;
  v *= sc;
  *p = v;
}

extern "C" void kernel_launch(void* const* d_in, const int* in_sizes, int n_in,
                              void* d_out, int out_size, void* d_ws, size_t ws_size,
                              hipStream_t stream) {
  const float* v0 = (const float*)d_in[0];
  const float* v1 = (const float*)d_in[1];
  const float* v2 = (const float*)d_in[2];
  const float* s0 = (const float*)d_in[3];
  const float* s1 = (const float*)d_in[4];
  const float* s2 = (const float*)d_in[5];
  const int* conn = (const int*)d_in[6];
  char* ws = (char*)d_ws;
  float* ss            = (float*)(ws + WS_SS);
  float* cg            = (float*)(ws + WS_CG);
  float* sx            = (float*)(ws + WS_SX);
  unsigned short* Abf  = (unsigned short*)(ws + WS_ABF);
  unsigned short* Pt   = (unsigned short*)(ws + WS_PT);
  float* out = (float*)d_out;

  k_pre  <<<dim3(6144),         dim3(256), 0, stream>>>(s0, s1, s2, sx, conn, Abf, ss, cg);
  k_cgp  <<<dim3(8, 16, B_),    dim3(256), 0, stream>>>(v0, v1, v2, sx, cg, Pt);
  k_gemm <<<dim3(208),          dim3(512), 0, stream>>>(Pt, Abf, out, ss);
  k_scale<<<dim3(13056),        dim3(256), 0, stream>>>(out, ss);
}

// Round 6
// 273.262 us; speedup vs baseline: 1.1207x; 1.0164x over previous
//
#include <hip/hip_runtime.h>
#include <math.h>

typedef __attribute__((ext_vector_type(8))) short short8;
typedef __attribute__((ext_vector_type(4))) float f32x4;

#define B_   4
#define N_   1024
#define FTOT 3264
#define FPAD 3328

// workspace offsets (bytes)
#define WS_SS   0
#define WS_CG   256
#define WS_SX   4096
#define WS_ABF  151552
#define WS_PT   8540160
// total ws use: 35,803,136 bytes

__device__ __forceinline__ unsigned short f2bf(float x) {
  union { float f; unsigned u; } v; v.f = x;
  unsigned r = v.u + 0x7FFFu + ((v.u >> 16) & 1u);
  return (unsigned short)(r >> 16);
}

__device__ __forceinline__ void gload16(const void* gp, void* lp) {
  __builtin_amdgcn_global_load_lds((const __attribute__((address_space(1))) unsigned int*)gp,
                                   (__attribute__((address_space(3))) unsigned int*)lp, 16, 0, 0);
}

__device__ __forceinline__ float wave_sum(float v) {
#pragma unroll
  for (int off = 32; off > 0; off >>= 1) v += __shfl_down(v, off, 64);
  return v;
}

// ---------------- CG coefficient machinery ----------------
__device__ double dfact(int n) { double r = 1.0; for (int i = 2; i <= n; ++i) r *= (double)i; return r; }

__device__ float cg_coeff(int l1, int m1, int l2, int m2, int L, int M) {
  if (m1 + m2 != M) return 0.f;
  int dl = l1 - l2; if (dl < 0) dl = -dl;
  if (L < dl || L > l1 + l2) return 0.f;
  double pre = sqrt((double)(2*L+1) * dfact(L+l1-l2) * dfact(L-l1+l2) * dfact(l1+l2-L) / dfact(l1+l2+L+1));
  pre *= sqrt(dfact(L+M)*dfact(L-M)*dfact(l1-m1)*dfact(l1+m1)*dfact(l2-m2)*dfact(l2+m2));
  double s = 0.0;
  for (int k = 0; k <= l1 + l2 - L; ++k) {
    int d1 = l1+l2-L-k, d2 = l1-m1-k, d3 = l2+m2-k, d4 = L-l2+m1+k, d5 = L-l1-m2+k;
    if (d1 < 0 || d2 < 0 || d3 < 0 || d4 < 0 || d5 < 0) continue;
    double t = (k & 1) ? -1.0 : 1.0;
    t /= dfact(k)*dfact(d1)*dfact(d2)*dfact(d3)*dfact(d4)*dfact(d5);
    s += t;
  }
  return (float)(pre * s);
}

// 15 CG tables in (L, frag) order; dense [i][j][k] layout, offsets below.
__device__ const int t_l1[15]  = {0,1,2, 0,1,1,1,2,2, 0,1,1,2,2,2};
__device__ const int t_l2[15]  = {0,1,2, 1,0,1,2,1,2, 2,1,2,0,1,2};
__device__ const int t_L [15]  = {0,0,0, 1,1,1,1,1,1, 2,2,2,2,2,2};
__device__ const int t_off[16] = {0,1,10, 35,44,53,80,125,170, 245,270,315,390,415,490, 615};

// per-L frag decode tables (frag order = reference's (l1,l2) loop order)
__device__ const int d_l1[3][6]  = {{0,1,2,0,0,0},{0,1,1,1,2,2},{0,1,1,2,2,2}};
__device__ const int d_l2[3][6]  = {{0,1,2,0,0,0},{1,0,1,2,1,2},{2,1,2,0,1,2}};
__device__ const int d_off[3][6] = {{0,1,10,0,0,0},{35,44,53,80,125,170},{245,270,315,390,415,490}};
__device__ const int d_rb[3] = {0, 1, 4};   // row base of degree l in the 9-row (m) stack

// K_pre: fused k_sx (blocks 0..4095) + k_adj (blocks 4096..6143) + init (block 4096).
__global__ __launch_bounds__(256) void k_pre(const float* __restrict__ s0p, const float* __restrict__ s1p,
                                             const float* __restrict__ s2p, float* __restrict__ sx,
                                             const int* __restrict__ conn, unsigned short* __restrict__ Abf,
                                             float* __restrict__ ss, float* __restrict__ cg) {
  __shared__ float red[9][256];
  const int tid = threadIdx.x;

  if (blockIdx.x < 4096) {
    const int bn = blockIdx.x;
    const f32x4* p0 = (const f32x4*)(s0p + (size_t)bn * 1024);
    const f32x4* p1 = (const f32x4*)(s1p + (size_t)bn * 3072);
    const f32x4* p2 = (const f32x4*)(s2p + (size_t)bn * 5120);

    // issue all 9 loads up front (independent -> deep vmcnt pipeline)
    f32x4 va = p0[tid];
    f32x4 vb[3];
#pragma unroll
    for (int it = 0; it < 3; ++it) vb[it] = p1[tid + 256 * it];
    f32x4 vc[5];
#pragma unroll
    for (int it = 0; it < 5; ++it) vc[it] = p2[tid + 256 * it];

    // s0: all elements are phase 0
    float a = va[0] + va[1] + va[2] + va[3];

    // s1: float idx = 4*tid + 1024*it + e; phase = (tid + it + e) mod 3; slot u=(it+e)%3
    float b[3] = {0.f, 0.f, 0.f};
#pragma unroll
    for (int it = 0; it < 3; ++it)
#pragma unroll
      for (int e = 0; e < 4; ++e)
        b[(it + e) % 3] += vb[it][e];

    // s2: float idx = 4*tid + 1024*it + e; phase = (4*tid + 4*it + e) mod 5; slot u=(4it+e)%5
    float c[5] = {0.f, 0.f, 0.f, 0.f, 0.f};
#pragma unroll
    for (int it = 0; it < 5; ++it)
#pragma unroll
      for (int e = 0; e < 4; ++e)
        c[(4 * it + e) % 5] += vc[it][e];

    // phase-indexed scatter (runtime rotation only in the LDS address)
    red[0][tid] = a;
    const int r3 = tid % 3;
#pragma unroll
    for (int u = 0; u < 3; ++u) red[1 + (r3 + u) % 3][tid] = b[u];
    const int q5 = (4 * tid) % 5;
#pragma unroll
    for (int u = 0; u < 5; ++u) red[4 + (q5 + u) % 5][tid] = c[u];
    __syncthreads();

    // wave w reduces rows w, w+4, w+8 (no further barriers)
    const int lane = tid & 63, w = tid >> 6;
    for (int r = w; r < 9; r += 4) {
      float v = red[r][lane] + red[r][lane + 64] + red[r][lane + 128] + red[r][lane + 192];
      v = wave_sum(v);
      if (lane == 0) sx[(size_t)bn * 9 + r] = v;
    }
    return;
  }

  // ---- adjacency part (blocks 4096..6143) ----
  const int idx  = (blockIdx.x - 4096) * 256 + tid;   // 0..524287
  const int lane = idx & 63;
  const int w    = (idx >> 6) & 2047;                 // wave within batch
  const int b    = idx >> 17;
  const int nt16 = w >> 5;                            // 16-row n tile (0..63)
  const int ks   = w & 31;
  const int l16  = lane & 15, quad = lane >> 4;
  const int n    = nt16 * 16 + l16;
  const int m8   = ks * 32 + quad * 8;
  const int4* src = (const int4*)(conn + ((size_t)(b * 1024 + n) * 1024 + m8));
  int4 c0 = src[0], c1 = src[1];
  short8 o;
  o[0] = f2bf((float)c0.x); o[1] = f2bf((float)c0.y);
  o[2] = f2bf((float)c0.z); o[3] = f2bf((float)c0.w);
  o[4] = f2bf((float)c1.x); o[5] = f2bf((float)c1.y);
  o[6] = f2bf((float)c1.z); o[7] = f2bf((float)c1.w);
  const int nt = n >> 7, nr = n & 127;
  *(short8*)&Abf[(size_t)(b * 8 + nt) * 131072 + ks * 4096 +
                 ((nr >> 4) * 4 + quad) * 128 + (nr & 15) * 8] = o;

  // ---- init part (block 4096 only): zero ss + counter, build CG table ----
  if (blockIdx.x == 4096) {
    if (tid < 4) ss[tid] = 0.f;
    for (int t0 = tid; t0 < 615; t0 += 256) {
      int t = 0;
      while (t < 14 && t0 >= t_off[t+1]) ++t;
      int local = t0 - t_off[t];
      int l1 = t_l1[t], l2 = t_l2[t], L = t_L[t];
      int nk = 2*L+1, n2 = 2*l2+1;
      int k = local % nk; int rest = local / nk;
      int j = rest % n2;  int i = rest / n2;
      cg[t0] = cg_coeff(l1, i - l1, l2, j - l2, L, k - L);
    }
  }
}

// K3: CG products -> PtT[b][ft(26)][ks(32)][fragment-major chunk] (bf16, padded to 3328)
#define VSTRIDE 148   // floats per m-row: 144 data + 4 pad

template <int L>
__device__ __forceinline__ void cg_emit(const float* __restrict__ vme, const float sxr[9],
                                        const float* __restrict__ cgt,
                                        unsigned short* __restrict__ pout, int cbase) {
  const int nfrag = (L == 0) ? 3 : 6;
  const int nk = 2 * L + 1;
  const int Lbase = (L == 0) ? 0 : (L == 1 ? 192 : 1344);
  const int Cfrag = nfrag * 64;
#pragma unroll
  for (int frag = 0; frag < nfrag; ++frag) {
    const int l1 = d_l1[L][frag], l2 = d_l2[L][frag];
    const int n1 = 2 * l1 + 1, n2 = 2 * l2 + 1;
    const int rb1 = d_rb[l1], rb2 = d_rb[l2];
    const int cgo = d_off[L][frag];
#pragma unroll
    for (int k = 0; k < nk; ++k) {
      float w[5];
#pragma unroll
      for (int i = 0; i < n1; ++i) {
        float a = 0.f;
#pragma unroll
        for (int j = 0; j < n2; ++j)
          a += sxr[rb2 + j] * cgt[cgo + (i * n2 + j) * nk + k];
        w[i] = a;
      }
      f32x4 val = {0.f, 0.f, 0.f, 0.f};
#pragma unroll
      for (int i = 0; i < n1; ++i) {
        f32x4 vv = *(const f32x4*)(vme + (rb1 + i) * 16);
        val += vv * w[i];
      }
      const int fb = Lbase + k * Cfrag + frag * 64 + cbase;
      const int ftile = fb >> 7, fr = fb & 127;
      unsigned short* pp = pout + (size_t)ftile * 131072 + (fr >> 4) * 512 + (fr & 15) * 8;
#pragma unroll
      for (int cc = 0; cc < 4; ++cc)
        pp[cc * 8] = f2bf(val[cc]);
    }
  }
}

__global__ __launch_bounds__(256) void k_cgp(const float* __restrict__ v0, const float* __restrict__ v1,
                                             const float* __restrict__ v2, const float* __restrict__ sx,
                                             const float* __restrict__ cgt, unsigned short* __restrict__ Pt) {
  __shared__ float vsh[64 * VSTRIDE];
  const int half = blockIdx.x & 1;
  const int cq   = blockIdx.x >> 1;
  const int mt   = blockIdx.y;
  const int b    = blockIdx.z;
  const int m0 = mt * 64;
  const int c0 = cq * 16;
  const int tid = threadIdx.x;
  const size_t nb = (size_t)b * N_ + m0;

  // vectorized v-tile load+transpose: thread = (m, c-quad); 9 aligned f32x4 each
  {
    const int mloc = tid >> 2;            // 0..63
    const int cc0  = (tid & 3) * 4;       // 0,4,8,12
    const size_t vrow = nb + mloc;
    *(f32x4*)&vsh[mloc*VSTRIDE + 0*16 + cc0] = *(const f32x4*)&v0[vrow * 64 + c0 + cc0];
#pragma unroll
    for (int r = 1; r < 4; ++r)
      *(f32x4*)&vsh[mloc*VSTRIDE + r*16 + cc0] = *(const f32x4*)&v1[(vrow * 3 + (r-1)) * 64 + c0 + cc0];
#pragma unroll
    for (int r = 4; r < 9; ++r)
      *(f32x4*)&vsh[mloc*VSTRIDE + r*16 + cc0] = *(const f32x4*)&v2[(vrow * 5 + (r-4)) * 64 + c0 + cc0];
  }
  const int lane = tid & 63, wv = tid >> 6;
  float sxr[9];
#pragma unroll
  for (int r = 0; r < 9; ++r) sxr[r] = sx[(nb + lane) * 9 + r];
  __syncthreads();

  const int ks = mt * 2 + (lane >> 5);
  const int kq = ((lane & 31) >> 3) * 128 + (lane & 7);
  unsigned short* pout = Pt + (size_t)b * 26 * 131072 + ks * 4096 + kq;
  const int cbase = c0 + wv * 4;
  const float* vme = &vsh[lane * VSTRIDE + wv * 4];

  if (half == 0) {
    cg_emit<0>(vme, sxr, cgt, pout, cbase);
    cg_emit<1>(vme, sxr, cgt, pout, cbase);
  } else {
    cg_emit<2>(vme, sxr, cgt, pout, cbase);
    const int fr = 64 + cbase;
    unsigned short* pp = pout + (size_t)25 * 131072 + (fr >> 4) * 512 + (fr & 15) * 8;
#pragma unroll
    for (int cc = 0; cc < 4; ++cc)
      pp[cc * 8] = 0;
  }
}

// K4: mp[b][n][f] = sum_m PtT*AbT, with fused normalization.
// 256x256 tile, BK=64, 512 thr (8 waves 2x4), LDS 128KB (2-stage dbuf),
// vmcnt(8) depth-2 pipeline. Grid 208 blocks, 1 block/CU (LDS-bound) ->
// all co-resident: device spin-barrier on ssv[3] after the norm atomics,
// then each block scales its acc in registers and writes out ONCE (k_scale
// eliminated; saves 107MB of out re-read/re-write traffic).
#define WAIT_VM8 0x0F78   // vmcnt=8, expcnt/lgkmcnt nowait
#define WAIT_VM0 0x0F70   // vmcnt=0
#define NBLK 208

__global__ __launch_bounds__(512, 2) void k_gemm(const unsigned short* __restrict__ PtT,
                                                 const unsigned short* __restrict__ AbT,
                                                 float* __restrict__ out, float* __restrict__ ssv) {
  __shared__ unsigned short As[2][2][8192];   // [buf][h: f-half 128 rows][2 ks-chunks]
  __shared__ unsigned short Bs[2][2][8192];   // [buf][h: n-half 128 rows][2 ks-chunks]
  const int i  = blockIdx.x;          // 0..207
  const int x  = i & 7, j = i >> 3;   // x: XCD bucket, j: 0..25
  const int b   = x >> 1;
  const int ntp = 2 * (x & 1) + (j & 1);   // 0..3  (256-n tile)
  const int ftp = j >> 1;                  // 0..12 (256-f tile)
  const int f0 = ftp * 256, n0 = ntp * 256;
  const int tid  = threadIdx.x;
  const int w    = tid >> 6, lane = tid & 63;
  const int wr   = w >> 2, wc = w & 3;     // wave grid 2(M) x 4(N)
  const int l16  = lane & 15, quad = lane >> 4;

  const unsigned short* gA0 = PtT + (size_t)(b * 26 + 2 * ftp    ) * 131072;
  const unsigned short* gA1 = PtT + (size_t)(b * 26 + 2 * ftp + 1) * 131072;
  const unsigned short* gB0 = AbT + (size_t)(b * 8  + 2 * ntp    ) * 131072;
  const unsigned short* gB1 = AbT + (size_t)(b * 8  + 2 * ntp + 1) * 131072;
  const int so = w * 512 + lane * 8;   // per-thread global short offset within a round

#define ISSUE(T, BUF) do { \
    const size_t o = (size_t)(T) * 8192 + so; \
    gload16(gA0 + o,        &As[BUF][0][w * 512]); \
    gload16(gA0 + o + 4096, &As[BUF][0][4096 + w * 512]); \
    gload16(gA1 + o,        &As[BUF][1][w * 512]); \
    gload16(gA1 + o + 4096, &As[BUF][1][4096 + w * 512]); \
    gload16(gB0 + o,        &Bs[BUF][0][w * 512]); \
    gload16(gB0 + o + 4096, &Bs[BUF][0][4096 + w * 512]); \
    gload16(gB1 + o,        &Bs[BUF][1][w * 512]); \
    gload16(gB1 + o + 4096, &Bs[BUF][1][4096 + w * 512]); \
  } while (0)

  f32x4 acc[8][4] = {};
  const int bh  = wc >> 1;            // B half this wave reads
  const int bl4 = (wc & 1) * 4;       // 16-row group base within that half

#define COMPUTE(BUF) do { \
    _Pragma("unroll") \
    for (int kc = 0; kc < 2; ++kc) { \
      short8 bf[4]; \
      _Pragma("unroll") \
      for (int ni = 0; ni < 4; ++ni) \
        bf[ni] = *(const short8*)&Bs[BUF][bh][kc*4096 + ((bl4 + ni)*4 + quad)*128 + l16*8]; \
      _Pragma("unroll") \
      for (int mh = 0; mh < 2; ++mh) { \
        short8 af[4]; \
        _Pragma("unroll") \
        for (int m = 0; m < 4; ++m) \
          af[m] = *(const short8*)&As[BUF][wr][kc*4096 + ((mh*4 + m)*4 + quad)*128 + l16*8]; \
        _Pragma("unroll") \
        for (int m = 0; m < 4; ++m) \
          _Pragma("unroll") \
          for (int ni = 0; ni < 4; ++ni) \
            acc[mh*4 + m][ni] = __builtin_amdgcn_mfma_f32_16x16x32_bf16(af[m], bf[ni], acc[mh*4 + m][ni], 0, 0, 0); \
      } \
    } \
  } while (0)

  ISSUE(0, 0);
  ISSUE(1, 1);
  for (int t = 0; t < 15; ++t) {
    const int buf = t & 1;
    __builtin_amdgcn_s_waitcnt(WAIT_VM8);   // tile t landed; tile t+1 stays in flight
    __builtin_amdgcn_s_barrier();
    COMPUTE(buf);
    __builtin_amdgcn_s_barrier();           // all waves done reading buf
    if (t < 14) ISSUE(t + 2, buf);
  }
  __builtin_amdgcn_s_waitcnt(WAIT_VM0);     // tail: tile 15
  __builtin_amdgcn_s_barrier();
  COMPUTE(1);

  // ---- epilogue pass 1: per-L sumsq of UNSCALED acc (norm is over unscaled mp) ----
  float ssl0 = 0.f, ssl1 = 0.f, ssl2 = 0.f;
#pragma unroll
  for (int mi = 0; mi < 8; ++mi) {
    const int fbase = f0 + wr*128 + mi*16 + quad*4;   // L boundaries are 16-aligned
    if (fbase >= FTOT) continue;
    float sq = 0.f;
#pragma unroll
    for (int ni = 0; ni < 4; ++ni) {
      f32x4 v = acc[mi][ni];
      sq += v[0]*v[0] + v[1]*v[1] + v[2]*v[2] + v[3]*v[3];
    }
    if (fbase < 192) ssl0 += sq; else if (fbase < 1344) ssl1 += sq; else ssl2 += sq;
  }
  ssl0 = wave_sum(ssl0); ssl1 = wave_sum(ssl1); ssl2 = wave_sum(ssl2);

  __syncthreads();                           // LDS free for reuse
  float* red = (float*)&As[0][0][0];
  if (lane == 0) { red[w*3 + 0] = ssl0; red[w*3 + 1] = ssl1; red[w*3 + 2] = ssl2; }
  __syncthreads();
  if (tid < 3) {
    float s = 0.f;
#pragma unroll
    for (int ww = 0; ww < 8; ++ww) s += red[ww*3 + tid];
    if (s != 0.f) atomicAdd(&ssv[tid], s);
  }
  // barrier drains vmcnt -> this block's value atomics complete at coherent point
  __syncthreads();

  // ---- device spin barrier (all 208 blocks co-resident: 1 block/CU by LDS) ----
  int* cnt = (int*)(ssv + 3);                // zeroed by k_pre each launch
  if (tid == 0) {
    __threadfence();
    atomicAdd(cnt, 1);                       // arrival
    while (atomicAdd(cnt, 0) < NBLK) __builtin_amdgcn_s_sleep(8);
  }
  __syncthreads();

  // broadcast norms (device-scope RMW read -> coherent), compute scales
  if (tid < 3) red[tid] = atomicAdd(&ssv[tid], 0.f);
  __syncthreads();
  const float sc0 = 64.f / (1.f * sqrtf(red[0]));
  const float sc1 = 64.f / (3.f * sqrtf(red[1]));
  const float sc2 = 64.f / (5.f * sqrtf(red[2]));

  // ---- epilogue pass 2: scaled store (out written exactly once) ----
#pragma unroll
  for (int mi = 0; mi < 8; ++mi) {
    const int fbase = f0 + wr*128 + mi*16 + quad*4;
    if (fbase >= FTOT) continue;
    const float sc = fbase < 192 ? sc0 : (fbase < 1344 ? sc1 : sc2);
#pragma unroll
    for (int ni = 0; ni < 4; ++ni) {
      const int n = n0 + wc*64 + ni*16 + l16;
      f32x4 v = acc[mi][ni];
      v *= sc;
      *(f32x4*)&out[((size_t)b * N_ + n) * FTOT + fbase] = v;
    }
  }
#undef ISSUE
#undef COMPUTE
}

extern "C" void kernel_launch(void* const* d_in, const int* in_sizes, int n_in,
                              void* d_out, int out_size, void* d_ws, size_t ws_size,
                              hipStream_t stream) {
  const float* v0 = (const float*)d_in[0];
  const float* v1 = (const float*)d_in[1];
  const float* v2 = (const float*)d_in[2];
  const float* s0 = (const float*)d_in[3];
  const float* s1 = (const float*)d_in[4];
  const float* s2 = (const float*)d_in[5];
  const int* conn = (const int*)d_in[6];
  char* ws = (char*)d_ws;
  float* ss            = (float*)(ws + WS_SS);
  float* cg            = (float*)(ws + WS_CG);
  float* sx            = (float*)(ws + WS_SX);
  unsigned short* Abf  = (unsigned short*)(ws + WS_ABF);
  unsigned short* Pt   = (unsigned short*)(ws + WS_PT);
  float* out = (float*)d_out;

  k_pre  <<<dim3(6144),         dim3(256), 0, stream>>>(s0, s1, s2, sx, conn, Abf, ss, cg);
  k_cgp  <<<dim3(8, 16, B_),    dim3(256), 0, stream>>>(v0, v1, v2, sx, cg, Pt);
  k_gemm <<<dim3(208),          dim3(512), 0, stream>>>(Pt, Abf, out, ss);
}